// Round 8
// baseline (330.055 us; speedup 1.0000x reference)
//
#include <hip/hip_runtime.h>
#include <hip/hip_bf16.h>
#include <stdint.h>

// Problem constants
#define BB 16
#define SS 2048
#define HH 1024

using bf16 = __hip_bfloat16;
typedef __attribute__((ext_vector_type(8))) short short8;
typedef __attribute__((ext_vector_type(4))) float f32x4;

typedef unsigned int __attribute__((address_space(1))) as1_uint;
typedef unsigned int __attribute__((address_space(3))) as3_uint;

// ---------------- workspace layout (bytes) ----------------
static constexpr size_t WS_XB   = 0;          // bf16[16*2048*1024]
static constexpr size_t WS_G    = 67108864;   // bf16[32768*1024]
static constexpr size_t WS_P    = 134217728;  // fp8 [32768*2048]
static constexpr size_t WS_WQT  = 134217728;  // aliased, dead before P written
static constexpr size_t WS_WKT  = 136314880;
static constexpr size_t WS_MT   = 138412032;
static constexpr size_t WS_LSUM = 201326592;  // f32[32768]
static constexpr size_t WS_T    = 201457664;  // f32[16*1024]
static constexpr size_t WS_NEED = 201523200;

__device__ __forceinline__ void async_copy16(bf16* lds_dst, const bf16* gsrc) {
    __builtin_amdgcn_global_load_lds((const as1_uint*)gsrc, (as3_uint*)lds_dst, 16, 0, 0);
}

__device__ __forceinline__ float bf2f(unsigned short u) {
    union { unsigned i; float f; } v; v.i = (unsigned)u << 16; return v.f;
}

__device__ __forceinline__ float fast_exp(float x) {
#if __has_builtin(__builtin_amdgcn_exp2f)
    return __builtin_amdgcn_exp2f(x * 1.4426950408889634f);
#else
    return __expf(x);
#endif
}

// ---------------- fp8 e4m3 encode/decode ----------------
__device__ __forceinline__ unsigned char f32_to_e4m3(float x) {
#if __has_builtin(__builtin_amdgcn_cvt_pk_fp8_f32)
    return (unsigned char)(__builtin_amdgcn_cvt_pk_fp8_f32(x, x, 0, false) & 0xff);
#else
    if (x >= 0.015625f) {
        union { float f; unsigned u; } v; v.f = x;
        int e = (v.u >> 23) & 0xff;
        unsigned m = v.u & 0x7fffff;
        unsigned mant = m >> 20;
        unsigned rem = m & 0xfffff;
        mant += (rem > 0x80000u) || (rem == 0x80000u && (mant & 1));
        int oe = e - 120;
        if (mant == 8) { mant = 0; oe += 1; }
        return (unsigned char)((oe << 3) | mant);
    }
    int code = (int)rintf(x * 512.0f);
    return (unsigned char)code;
#endif
}

__device__ __forceinline__ float e4m3_to_f32(unsigned char b) {
#if __has_builtin(__builtin_amdgcn_cvt_pk_f32_fp8)
    auto v = __builtin_amdgcn_cvt_pk_f32_fp8((int)b, false);
    return v[0];
#else
    int e = (b >> 3) & 15, m = b & 7;
    if (e) { union { unsigned u; float f; } v; v.u = ((unsigned)(e + 120) << 23) | ((unsigned)m << 20); return v.f; }
    return (float)m * 0.001953125f;
#endif
}

// ---------------- cast x -> bf16 ----------------
__global__ __launch_bounds__(256) void cast_x_kernel(const float* __restrict__ x,
                                                     bf16* __restrict__ xb, int n4) {
    int stride = gridDim.x * blockDim.x;
    for (int i = blockIdx.x * blockDim.x + threadIdx.x; i < n4; i += stride) {
        float4 v = reinterpret_cast<const float4*>(x)[i];
        union { bf16 h[4]; uint2 u; } p;
        p.h[0] = __float2bfloat16(v.x); p.h[1] = __float2bfloat16(v.y);
        p.h[2] = __float2bfloat16(v.z); p.h[3] = __float2bfloat16(v.w);
        reinterpret_cast<uint2*>(xb)[i] = p.u;
    }
}

// ---------------- transpose-cast W -> WT bf16 (i,o) ----------------
__global__ __launch_bounds__(256) void transpose_w_kernel(const float* __restrict__ wq,
                                                          const float* __restrict__ wk,
                                                          bf16* __restrict__ wqT,
                                                          bf16* __restrict__ wkT) {
    __shared__ float tile[64][65];
    const float* src = blockIdx.z ? wk : wq;
    bf16* dst = blockIdx.z ? wkT : wqT;
    const int o0 = blockIdx.y * 64, i0 = blockIdx.x * 64;
    const int tr = threadIdx.x >> 4;
    const int tc = (threadIdx.x & 15) * 4;
#pragma unroll
    for (int k = 0; k < 4; ++k) {
        float4 v = *reinterpret_cast<const float4*>(src + (size_t)(o0 + tr + k * 16) * 1024 + i0 + tc);
        tile[tr + k * 16][tc + 0] = v.x; tile[tr + k * 16][tc + 1] = v.y;
        tile[tr + k * 16][tc + 2] = v.z; tile[tr + k * 16][tc + 3] = v.w;
    }
    __syncthreads();
#pragma unroll
    for (int k = 0; k < 4; ++k) {
        int ri = tr + k * 16;
        union { bf16 h[4]; uint2 u; } p;
#pragma unroll
        for (int j = 0; j < 4; ++j) p.h[j] = __float2bfloat16(tile[tc + j][ri]);
        *reinterpret_cast<uint2*>(dst + (size_t)(i0 + ri) * 1024 + o0 + tc) = p.u;
    }
}

// ---------------- gemm_mt64: Mt[j][i] = (1/32) sum_o Wk[o,j]*Wq[o,i], 64x64 tiles ----------------
__global__ __launch_bounds__(256) void gemm_mt64(const bf16* __restrict__ wkT,
                                                 const bf16* __restrict__ wqT,
                                                 bf16* __restrict__ Mt) {
    __shared__ bf16 As[64 * 64], Bs[64 * 64];
    f32x4 acc[2][2];
#pragma unroll
    for (int m = 0; m < 2; ++m)
#pragma unroll
        for (int n = 0; n < 2; ++n) { acc[m][n][0]=0.f; acc[m][n][1]=0.f; acc[m][n][2]=0.f; acc[m][n][3]=0.f; }
    const int tid = threadIdx.x, wid = tid >> 6, lane = tid & 63;
    const int wm = wid >> 1, wn = wid & 1;
    const int srow = lane >> 3, scol = (lane & 7) * 8;
    const bf16* Ab = wkT + (size_t)blockIdx.y * 64 * 1024;
    const bf16* Bb = wqT + (size_t)blockIdx.x * 64 * 1024;
    for (int kt = 0; kt < 1024; kt += 64) {
#pragma unroll
        for (int i = 0; i < 2; ++i) {
            int row0 = i * 32 + wid * 8;  // wave-uniform
            async_copy16(As + row0 * 64, Ab + (size_t)(row0 + srow) * 1024 + kt + scol);
            async_copy16(Bs + row0 * 64, Bb + (size_t)(row0 + srow) * 1024 + kt + scol);
        }
        __syncthreads();
#pragma unroll
        for (int kk = 0; kk < 2; ++kk) {
            short8 a[2], b[2];
#pragma unroll
            for (int m = 0; m < 2; ++m)
                a[m] = *reinterpret_cast<const short8*>(
                    As + (wm * 32 + m * 16 + (lane & 15)) * 64 + kk * 32 + (lane >> 4) * 8);
#pragma unroll
            for (int n = 0; n < 2; ++n)
                b[n] = *reinterpret_cast<const short8*>(
                    Bs + (wn * 32 + n * 16 + (lane & 15)) * 64 + kk * 32 + (lane >> 4) * 8);
#pragma unroll
            for (int m = 0; m < 2; ++m)
#pragma unroll
                for (int n = 0; n < 2; ++n)
                    acc[m][n] = __builtin_amdgcn_mfma_f32_16x16x32_bf16(a[m], b[n], acc[m][n], 0, 0, 0);
        }
        __syncthreads();
    }
    const int row0 = blockIdx.y * 64 + wm * 32 + ((lane >> 4) << 2);
    const int col0 = blockIdx.x * 64 + wn * 32 + (lane & 15);
#pragma unroll
    for (int m = 0; m < 2; ++m)
#pragma unroll
        for (int n = 0; n < 2; ++n)
#pragma unroll
            for (int r = 0; r < 4; ++r)
                Mt[(size_t)(row0 + m * 16 + r) * 1024 + col0 + n * 16] =
                    __float2bfloat16(acc[m][n][r] * 0.03125f);
}

// ================= 256x256 2-phase overlap mainloop (R6 schedule, T1+T2+T4+T5) =================
// Per K-tile (BK=64):
//   top:  issue ds_reads b0(4),a0(8),b1(4); stage A1,B1[t+1]->other buf;
//         MFMA Q00+Q01 (compiler fine-grained lgkm waits -> reads stream under MFMA);
//         sched_barrier(0); mid-barrier
//   bot:  stage A0,B0[t+2]->cur buf q0 regions; issue ds_reads a1(8);
//         MFMA Q11+Q10; sched_barrier(0); vmcnt(4); boundary barrier.
static constexpr int NT256 = 16;  // K=1024 / BK=64

__device__ __forceinline__ void gemm256_mainloop(const bf16* __restrict__ Ag,
                                                 const bf16* __restrict__ Bg,
                                                 char* lds, f32x4 acc[8][4]) {
    const int tid = threadIdx.x;
    const int lane = tid & 63;
    const int wid = tid >> 6;
    const int wm = wid >> 2;   // 0..1
    const int wn = wid & 3;    // 0..3

#pragma unroll
    for (int m = 0; m < 8; ++m)
#pragma unroll
        for (int n = 0; n < 4; ++n) { acc[m][n][0]=0.f; acc[m][n][1]=0.f; acc[m][n][2]=0.f; acc[m][n][3]=0.f; }

    char* A0 = lds;            char* B0 = lds + 32768;
    char* A1 = lds + 65536;    char* B1 = lds + 98304;

    // ---- hoisted stage source offsets (elements) ----
    int soA[2], soB[2];
    {
#pragma unroll
        for (int i = 0; i < 2; ++i) {
            int beta = (i * 512 + tid) * 16;
            int rho  = beta >> 7;
            int cs   = (beta & 127) ^ ((rho & 7) << 4);
            soA[i] = ((rho >> 6) * 128 + (rho & 63)) * 1024 + (cs >> 1);
            soB[i] = ((rho >> 5) * 64  + (rho & 31)) * 1024 + (cs >> 1);
        }
    }
    const int dstw = wid * 1024;  // wave-uniform lds dst base within region half

    // ---- hoisted ds_read byte offsets (lower halves; upper = +16384, kk=1 = ^64) ----
    int roA[4], roB[2];
    {
        const int swz = (lane & 7) << 4;
        const int colb = (lane >> 4) * 16;
#pragma unroll
        for (int mi = 0; mi < 4; ++mi) {
            int row = wm * 64 + mi * 16 + (lane & 15);
            roA[mi] = (row * 128 + colb) ^ swz;
        }
#pragma unroll
        for (int ni = 0; ni < 2; ++ni) {
            int row = wn * 32 + ni * 16 + (lane & 15);
            roB[ni] = (row * 128 + colb) ^ swz;
        }
    }

#define STAGE_A256(buf, q, kt)                                                        \
    {                                                                                 \
        async_copy16((bf16*)((buf) + (q) * 16384 + dstw),                             \
                     Ag + soA[0] + (q) * 65536 + (kt) * 64);                          \
        async_copy16((bf16*)((buf) + (q) * 16384 + 8192 + dstw),                      \
                     Ag + soA[1] + (q) * 65536 + (kt) * 64);                          \
    }
#define STAGE_B256(buf, q, kt)                                                        \
    {                                                                                 \
        async_copy16((bf16*)((buf) + (q) * 16384 + dstw),                             \
                     Bg + soB[0] + (q) * 32768 + (kt) * 64);                          \
        async_copy16((bf16*)((buf) + (q) * 16384 + 8192 + dstw),                      \
                     Bg + soB[1] + (q) * 32768 + (kt) * 64);                          \
    }

    // Prologue: tile0 fully + tile1 {A0,B0}; wait the 8 oldest (tile0).
    STAGE_A256(A0, 0, 0); STAGE_A256(A0, 1, 0);
    STAGE_B256(B0, 0, 0); STAGE_B256(B0, 1, 0);
    STAGE_A256(A1, 0, 1); STAGE_B256(B1, 0, 1);
    asm volatile("s_waitcnt vmcnt(4)" ::: "memory");
    __builtin_amdgcn_s_barrier();

    short8 a[4][2], b0[2][2], b1[2][2];

#pragma unroll 1
    for (int t = 0; t < NT256; ++t) {
        char* As  = (t & 1) ? A1 : A0;
        char* Bs  = (t & 1) ? B1 : B0;
        char* Aso = (t & 1) ? A0 : A1;
        char* Bso = (t & 1) ? B0 : B1;

        // ======== top half: quadrants (0,0) then (0,1) ========
#pragma unroll
        for (int ni = 0; ni < 2; ++ni) {
            b0[ni][0] = *reinterpret_cast<const short8*>(Bs + roB[ni]);
            b0[ni][1] = *reinterpret_cast<const short8*>(Bs + (roB[ni] ^ 64));
        }
#pragma unroll
        for (int mi = 0; mi < 4; ++mi) {
            a[mi][0] = *reinterpret_cast<const short8*>(As + roA[mi]);
            a[mi][1] = *reinterpret_cast<const short8*>(As + (roA[mi] ^ 64));
        }
#pragma unroll
        for (int ni = 0; ni < 2; ++ni) {
            b1[ni][0] = *reinterpret_cast<const short8*>(Bs + (roB[ni] + 16384));
            b1[ni][1] = *reinterpret_cast<const short8*>(Bs + ((roB[ni] ^ 64) + 16384));
        }
        if (t + 1 < NT256) { STAGE_A256(Aso, 1, t + 1); STAGE_B256(Bso, 1, t + 1); }
        __builtin_amdgcn_s_setprio(1);
#pragma unroll
        for (int mi = 0; mi < 4; ++mi)
#pragma unroll
            for (int ni = 0; ni < 2; ++ni)
#pragma unroll
                for (int kk = 0; kk < 2; ++kk)
                    acc[mi][ni] = __builtin_amdgcn_mfma_f32_16x16x32_bf16(
                        a[mi][kk], b0[ni][kk], acc[mi][ni], 0, 0, 0);
#pragma unroll
        for (int mi = 0; mi < 4; ++mi)
#pragma unroll
            for (int ni = 0; ni < 2; ++ni)
#pragma unroll
                for (int kk = 0; kk < 2; ++kk)
                    acc[mi][2 + ni] = __builtin_amdgcn_mfma_f32_16x16x32_bf16(
                        a[mi][kk], b1[ni][kk], acc[mi][2 + ni], 0, 0, 0);
        __builtin_amdgcn_s_setprio(0);
        __builtin_amdgcn_sched_barrier(0);   // pin MFMAs + their lgkm waits above the barrier
        __builtin_amdgcn_s_barrier();        // all waves' q0-region reads complete

        // ======== bottom half: quadrants (1,1) then (1,0) ========
        if (t + 2 < NT256) { STAGE_A256(As, 0, t + 2); STAGE_B256(Bs, 0, t + 2); }
#pragma unroll
        for (int mi = 0; mi < 4; ++mi) {
            a[mi][0] = *reinterpret_cast<const short8*>(As + (roA[mi] + 16384));
            a[mi][1] = *reinterpret_cast<const short8*>(As + ((roA[mi] ^ 64) + 16384));
        }
        __builtin_amdgcn_s_setprio(1);
#pragma unroll
        for (int mi = 0; mi < 4; ++mi)
#pragma unroll
            for (int ni = 0; ni < 2; ++ni)
#pragma unroll
                for (int kk = 0; kk < 2; ++kk)
                    acc[4 + mi][2 + ni] = __builtin_amdgcn_mfma_f32_16x16x32_bf16(
                        a[mi][kk], b1[ni][kk], acc[4 + mi][2 + ni], 0, 0, 0);
#pragma unroll
        for (int mi = 0; mi < 4; ++mi)
#pragma unroll
            for (int ni = 0; ni < 2; ++ni)
#pragma unroll
                for (int kk = 0; kk < 2; ++kk)
                    acc[4 + mi][ni] = __builtin_amdgcn_mfma_f32_16x16x32_bf16(
                        a[mi][kk], b0[ni][kk], acc[4 + mi][ni], 0, 0, 0);
        __builtin_amdgcn_s_setprio(0);
        __builtin_amdgcn_sched_barrier(0);   // pin a1 reads/waits above the boundary
        if (t + 2 < NT256) asm volatile("s_waitcnt vmcnt(4)" ::: "memory");
        else               asm volatile("s_waitcnt vmcnt(0)" ::: "memory");
        __builtin_amdgcn_s_barrier();        // tile boundary: tile t+1 fully landed
    }
#undef STAGE_A256
#undef STAGE_B256
}

// ---------------- G = xb @ Mt^T  (32768x1024), 256², XCD-swizzled 1-D grid (512) ----------------
__global__ __launch_bounds__(512, 2) void gemm_g256(const bf16* __restrict__ xb,
                                                    const bf16* __restrict__ Mt,
                                                    bf16* __restrict__ G) {
    extern __shared__ char lds[];
    f32x4 acc[8][4];
    // XCD swizzle: 512 blocks = 8 XCD slabs of 64 contiguous tiles.
    const int l = (blockIdx.x & 7) * 64 + (blockIdx.x >> 3);
    const int by = l >> 2, bx = l & 3;
    gemm256_mainloop(xb + (size_t)by * 256 * 1024, Mt + (size_t)bx * 256 * 1024, lds, acc);
    const int lane = threadIdx.x & 63, wid = threadIdx.x >> 6;
    const int wm = wid >> 2, wn = wid & 3;
    const int row0 = by * 256 + wm * 128 + ((lane >> 4) << 2);
    const int col0 = bx * 256 + wn * 64 + (lane & 15);
#pragma unroll
    for (int mi = 0; mi < 8; ++mi)
#pragma unroll
        for (int ni = 0; ni < 4; ++ni)
#pragma unroll
            for (int r = 0; r < 4; ++r)
                G[(size_t)(row0 + mi * 16 + r) * 1024 + col0 + ni * 16] =
                    __float2bfloat16(acc[mi][ni][r]);
}

// ---------------- energy: E = G @ xb^T, P = fp8(exp(E)), lsum += rowsum(dec(P)) ----------------
// XCD-swizzled 1-D grid (1024): each XCD slab shares (bz,by) G-panels across the bx sweep.
__global__ __launch_bounds__(512, 2) void energy_fused256(const bf16* __restrict__ G,
                                                          const bf16* __restrict__ xb,
                                                          unsigned char* __restrict__ P,
                                                          float* __restrict__ lsum) {
    extern __shared__ char lds[];
    f32x4 acc[8][4];
    const int l = (blockIdx.x & 7) * 128 + (blockIdx.x >> 3);
    const int bz = l >> 6, by = (l >> 3) & 7, bx = l & 7;
    gemm256_mainloop(G + (size_t)(bz * 2048 + by * 256) * 1024,
                     xb + (size_t)(bz * 2048 + bx * 256) * 1024, lds, acc);
    const int lane = threadIdx.x & 63, wid = threadIdx.x >> 6;
    const int wm = wid >> 2, wn = wid & 3;
    const int q0 = bz * 2048 + by * 256 + wm * 128 + ((lane >> 4) << 2);
    const int k0 = bx * 256 + wn * 64 + (lane & 15);
#pragma unroll
    for (int mi = 0; mi < 8; ++mi) {
        float s[4] = {0.f, 0.f, 0.f, 0.f};
#pragma unroll
        for (int ni = 0; ni < 4; ++ni)
#pragma unroll
            for (int r = 0; r < 4; ++r) {
                float e = fast_exp(acc[mi][ni][r]);
                unsigned char c = f32_to_e4m3(e);
                P[(size_t)(q0 + mi * 16 + r) * 2048 + k0 + ni * 16] = c;
                s[r] += e4m3_to_f32(c);
            }
#pragma unroll
        for (int off = 1; off < 16; off <<= 1)
#pragma unroll
            for (int r = 0; r < 4; ++r) s[r] += __shfl_xor(s[r], off, 64);
        if ((lane & 15) == 0) {
#pragma unroll
            for (int r = 0; r < 4; ++r) atomicAdd(&lsum[q0 + mi * 16 + r], s[r]);
        }
    }
}

// ---------------- aw[b,k] = (1/S) sum_q dec(P[b,q,k]) / lsum[b,q] ----------------
__global__ __launch_bounds__(256) void colsum_kernel(const unsigned char* __restrict__ P,
                                                     const float* __restrict__ lsum,
                                                     float* __restrict__ aw) {
    const int b = blockIdx.y, qc = blockIdx.x, t = threadIdx.x;
    float acc[8] = {0.f, 0.f, 0.f, 0.f, 0.f, 0.f, 0.f, 0.f};
    const unsigned char* base = P + (size_t)(b * 2048 + qc * 128) * 2048 + t * 8;
    const float* ls = lsum + b * 2048 + qc * 128;
    for (int q = 0; q < 128; ++q) {
        float w = 1.0f / ls[q];
        uint2 v = *reinterpret_cast<const uint2*>(base + (size_t)q * 2048);
#if __has_builtin(__builtin_amdgcn_cvt_pk_f32_fp8)
        auto p0 = __builtin_amdgcn_cvt_pk_f32_fp8((int)v.x, false);
        auto p1 = __builtin_amdgcn_cvt_pk_f32_fp8((int)v.x, true);
        auto p2 = __builtin_amdgcn_cvt_pk_f32_fp8((int)v.y, false);
        auto p3 = __builtin_amdgcn_cvt_pk_f32_fp8((int)v.y, true);
        acc[0] += p0[0] * w; acc[1] += p0[1] * w;
        acc[2] += p1[0] * w; acc[3] += p1[1] * w;
        acc[4] += p2[0] * w; acc[5] += p2[1] * w;
        acc[6] += p3[0] * w; acc[7] += p3[1] * w;
#else
        unsigned char by8[8];
        *reinterpret_cast<uint2*>(by8) = v;
#pragma unroll
        for (int j = 0; j < 8; ++j) acc[j] += e4m3_to_f32(by8[j]) * w;
#endif
    }
#pragma unroll
    for (int j = 0; j < 8; ++j)
        atomicAdd(&aw[b * 2048 + t * 8 + j], acc[j] * (1.0f / 2048.0f));
}

// ---------------- t[b,h] = sum_k aw[b,k] * xb[b,k,h]  (bf16 x) ----------------
__global__ __launch_bounds__(256) void av_x_kernel(const float* __restrict__ aw,
                                                   const bf16* __restrict__ xb,
                                                   float* __restrict__ t) {
    const int b = blockIdx.y;
    const int kc = blockIdx.x;
    const int tid = threadIdx.x;
    float4 acc = {0.f, 0.f, 0.f, 0.f};
    const int k0 = kc * 128;
#pragma unroll 4
    for (int k = k0; k < k0 + 128; ++k) {
        float w = aw[b * 2048 + k];
        uint2 v = *reinterpret_cast<const uint2*>(xb + (size_t)(b * 2048 + k) * 1024 + tid * 4);
        acc.x += w * bf2f((unsigned short)(v.x & 0xffff));
        acc.y += w * bf2f((unsigned short)(v.x >> 16));
        acc.z += w * bf2f((unsigned short)(v.y & 0xffff));
        acc.w += w * bf2f((unsigned short)(v.y >> 16));
    }
    float* tp = t + b * 1024 + tid * 4;
    atomicAdd(tp + 0, acc.x); atomicAdd(tp + 1, acc.y);
    atomicAdd(tp + 2, acc.z); atomicAdd(tp + 3, acc.w);
}

// ---------------- context[b,o] = sum_h t[b,h] * W_v[o,h] ----------------
__global__ __launch_bounds__(256) void ctx_gemv_kernel(const float* __restrict__ t,
                                                       const float* __restrict__ wv,
                                                       float* __restrict__ ctx) {
    const int b = blockIdx.y;
    const int wid = threadIdx.x >> 6, lane = threadIdx.x & 63;
    const int o = blockIdx.x * 4 + wid;
    const float4* t4 = reinterpret_cast<const float4*>(t + b * 1024);
    const float4* w4 = reinterpret_cast<const float4*>(wv + (size_t)o * 1024);
    float s = 0.f;
#pragma unroll
    for (int j = lane; j < 256; j += 64) {
        float4 a = t4[j], w = w4[j];
        s += a.x * w.x + a.y * w.y + a.z * w.z + a.w * w.w;
    }
#pragma unroll
    for (int off = 1; off < 64; off <<= 1) s += __shfl_xor(s, off, 64);
    if (lane == 0) ctx[b * 1024 + o] = s;
}

__global__ void ws_too_small_kernel(float* out) {
    if (threadIdx.x == 0 && blockIdx.x == 0) out[0] = 12345.0f;
}

extern "C" void kernel_launch(void* const* d_in, const int* in_sizes, int n_in,
                              void* d_out, int out_size, void* d_ws, size_t ws_size,
                              hipStream_t stream) {
    const float* x  = (const float*)d_in[0];
    const float* wq = (const float*)d_in[1];
    const float* wk = (const float*)d_in[2];
    const float* wv = (const float*)d_in[3];
    float* out = (float*)d_out;
    float* ctx = out;           // 16*1024
    float* aw  = out + 16384;   // 16*2048

    if (ws_size < WS_NEED) {
        hipMemsetAsync(d_out, 0, (size_t)out_size * sizeof(float), stream);
        ws_too_small_kernel<<<1, 64, 0, stream>>>(out);
        return;
    }

    char* ws = (char*)d_ws;
    bf16* xb   = (bf16*)(ws + WS_XB);
    bf16* G    = (bf16*)(ws + WS_G);
    unsigned char* P = (unsigned char*)(ws + WS_P);
    bf16* wqT  = (bf16*)(ws + WS_WQT);
    bf16* wkT  = (bf16*)(ws + WS_WKT);
    bf16* Mt   = (bf16*)(ws + WS_MT);
    float* lsum = (float*)(ws + WS_LSUM);
    float* t    = (float*)(ws + WS_T);

    hipMemsetAsync(d_out, 0, (size_t)out_size * sizeof(float), stream);
    hipMemsetAsync(lsum, 0, 131072 + 65536, stream);  // lsum + t contiguous

    cast_x_kernel<<<2048, 256, 0, stream>>>(x, xb, (BB * SS * HH) / 4);
    transpose_w_kernel<<<dim3(16, 16, 2), 256, 0, stream>>>(wq, wk, wqT, wkT);

    gemm_mt64<<<dim3(16, 16), 256, 0, stream>>>(wkT, wqT, Mt);
    gemm_g256<<<512, 512, 131072, stream>>>(xb, Mt, G);

    energy_fused256<<<1024, 512, 131072, stream>>>(G, xb, P, lsum);
    colsum_kernel<<<dim3(16, 16), 256, 0, stream>>>(P, lsum, aw);

    av_x_kernel<<<dim3(16, 16), 256, 0, stream>>>(aw, xb, t);
    ctx_gemv_kernel<<<dim3(256, 16), 256, 0, stream>>>(t, wv, ctx);
}

// Round 9
// 327.836 us; speedup vs baseline: 1.0068x; 1.0068x over previous
//
#include <hip/hip_runtime.h>
#include <hip/hip_bf16.h>
#include <stdint.h>

// Problem constants
#define BB 16
#define SS 2048
#define HH 1024

using bf16 = __hip_bfloat16;
typedef __attribute__((ext_vector_type(8))) short short8;
typedef __attribute__((ext_vector_type(4))) float f32x4;

typedef unsigned int __attribute__((address_space(1))) as1_uint;
typedef unsigned int __attribute__((address_space(3))) as3_uint;

// ---------------- workspace layout (bytes) ----------------
static constexpr size_t WS_XB   = 0;          // bf16[16*2048*1024]
static constexpr size_t WS_G    = 67108864;   // bf16[32768*1024]
static constexpr size_t WS_P    = 134217728;  // fp8 PT[b][k][q] (transposed!)
static constexpr size_t WS_WQT  = 134217728;  // aliased, dead before P written
static constexpr size_t WS_WKT  = 136314880;
static constexpr size_t WS_MT   = 138412032;
static constexpr size_t WS_LSUM = 201326592;  // f32[32768]
static constexpr size_t WS_T    = 201457664;  // f32[16*1024]
static constexpr size_t WS_NEED = 201523200;

__device__ __forceinline__ void async_copy16(bf16* lds_dst, const bf16* gsrc) {
    __builtin_amdgcn_global_load_lds((const as1_uint*)gsrc, (as3_uint*)lds_dst, 16, 0, 0);
}

__device__ __forceinline__ float bf2f(unsigned short u) {
    union { unsigned i; float f; } v; v.i = (unsigned)u << 16; return v.f;
}

__device__ __forceinline__ float fast_exp(float x) {
#if __has_builtin(__builtin_amdgcn_exp2f)
    return __builtin_amdgcn_exp2f(x * 1.4426950408889634f);
#else
    return __expf(x);
#endif
}

// ---------------- fp8 e4m3 encode/decode ----------------
__device__ __forceinline__ unsigned char f32_to_e4m3(float x) {
#if __has_builtin(__builtin_amdgcn_cvt_pk_fp8_f32)
    return (unsigned char)(__builtin_amdgcn_cvt_pk_fp8_f32(x, x, 0, false) & 0xff);
#else
    if (x >= 0.015625f) {
        union { float f; unsigned u; } v; v.f = x;
        int e = (v.u >> 23) & 0xff;
        unsigned m = v.u & 0x7fffff;
        unsigned mant = m >> 20;
        unsigned rem = m & 0xfffff;
        mant += (rem > 0x80000u) || (rem == 0x80000u && (mant & 1));
        int oe = e - 120;
        if (mant == 8) { mant = 0; oe += 1; }
        return (unsigned char)((oe << 3) | mant);
    }
    int code = (int)rintf(x * 512.0f);
    return (unsigned char)code;
#endif
}

__device__ __forceinline__ float e4m3_to_f32(unsigned char b) {
#if __has_builtin(__builtin_amdgcn_cvt_pk_f32_fp8)
    auto v = __builtin_amdgcn_cvt_pk_f32_fp8((int)b, false);
    return v[0];
#else
    int e = (b >> 3) & 15, m = b & 7;
    if (e) { union { unsigned u; float f; } v; v.u = ((unsigned)(e + 120) << 23) | ((unsigned)m << 20); return v.f; }
    return (float)m * 0.001953125f;
#endif
}

// ---------------- cast x -> bf16 ----------------
__global__ __launch_bounds__(256) void cast_x_kernel(const float* __restrict__ x,
                                                     bf16* __restrict__ xb, int n4) {
    int stride = gridDim.x * blockDim.x;
    for (int i = blockIdx.x * blockDim.x + threadIdx.x; i < n4; i += stride) {
        float4 v = reinterpret_cast<const float4*>(x)[i];
        union { bf16 h[4]; uint2 u; } p;
        p.h[0] = __float2bfloat16(v.x); p.h[1] = __float2bfloat16(v.y);
        p.h[2] = __float2bfloat16(v.z); p.h[3] = __float2bfloat16(v.w);
        reinterpret_cast<uint2*>(xb)[i] = p.u;
    }
}

// ---------------- transpose-cast W -> WT bf16 (i,o) ----------------
__global__ __launch_bounds__(256) void transpose_w_kernel(const float* __restrict__ wq,
                                                          const float* __restrict__ wk,
                                                          bf16* __restrict__ wqT,
                                                          bf16* __restrict__ wkT) {
    __shared__ float tile[64][65];
    const float* src = blockIdx.z ? wk : wq;
    bf16* dst = blockIdx.z ? wkT : wqT;
    const int o0 = blockIdx.y * 64, i0 = blockIdx.x * 64;
    const int tr = threadIdx.x >> 4;
    const int tc = (threadIdx.x & 15) * 4;
#pragma unroll
    for (int k = 0; k < 4; ++k) {
        float4 v = *reinterpret_cast<const float4*>(src + (size_t)(o0 + tr + k * 16) * 1024 + i0 + tc);
        tile[tr + k * 16][tc + 0] = v.x; tile[tr + k * 16][tc + 1] = v.y;
        tile[tr + k * 16][tc + 2] = v.z; tile[tr + k * 16][tc + 3] = v.w;
    }
    __syncthreads();
#pragma unroll
    for (int k = 0; k < 4; ++k) {
        int ri = tr + k * 16;
        union { bf16 h[4]; uint2 u; } p;
#pragma unroll
        for (int j = 0; j < 4; ++j) p.h[j] = __float2bfloat16(tile[tc + j][ri]);
        *reinterpret_cast<uint2*>(dst + (size_t)(i0 + ri) * 1024 + o0 + tc) = p.u;
    }
}

// ---------------- gemm_mt64: Mt[j][i] = (1/32) sum_o Wk[o,j]*Wq[o,i], 64x64 tiles ----------------
__global__ __launch_bounds__(256) void gemm_mt64(const bf16* __restrict__ wkT,
                                                 const bf16* __restrict__ wqT,
                                                 bf16* __restrict__ Mt) {
    __shared__ bf16 As[64 * 64], Bs[64 * 64];
    f32x4 acc[2][2];
#pragma unroll
    for (int m = 0; m < 2; ++m)
#pragma unroll
        for (int n = 0; n < 2; ++n) { acc[m][n][0]=0.f; acc[m][n][1]=0.f; acc[m][n][2]=0.f; acc[m][n][3]=0.f; }
    const int tid = threadIdx.x, wid = tid >> 6, lane = tid & 63;
    const int wm = wid >> 1, wn = wid & 1;
    const int srow = lane >> 3, scol = (lane & 7) * 8;
    const bf16* Ab = wkT + (size_t)blockIdx.y * 64 * 1024;
    const bf16* Bb = wqT + (size_t)blockIdx.x * 64 * 1024;
    for (int kt = 0; kt < 1024; kt += 64) {
#pragma unroll
        for (int i = 0; i < 2; ++i) {
            int row0 = i * 32 + wid * 8;  // wave-uniform
            async_copy16(As + row0 * 64, Ab + (size_t)(row0 + srow) * 1024 + kt + scol);
            async_copy16(Bs + row0 * 64, Bb + (size_t)(row0 + srow) * 1024 + kt + scol);
        }
        __syncthreads();
#pragma unroll
        for (int kk = 0; kk < 2; ++kk) {
            short8 a[2], b[2];
#pragma unroll
            for (int m = 0; m < 2; ++m)
                a[m] = *reinterpret_cast<const short8*>(
                    As + (wm * 32 + m * 16 + (lane & 15)) * 64 + kk * 32 + (lane >> 4) * 8);
#pragma unroll
            for (int n = 0; n < 2; ++n)
                b[n] = *reinterpret_cast<const short8*>(
                    Bs + (wn * 32 + n * 16 + (lane & 15)) * 64 + kk * 32 + (lane >> 4) * 8);
#pragma unroll
            for (int m = 0; m < 2; ++m)
#pragma unroll
                for (int n = 0; n < 2; ++n)
                    acc[m][n] = __builtin_amdgcn_mfma_f32_16x16x32_bf16(a[m], b[n], acc[m][n], 0, 0, 0);
        }
        __syncthreads();
    }
    const int row0 = blockIdx.y * 64 + wm * 32 + ((lane >> 4) << 2);
    const int col0 = blockIdx.x * 64 + wn * 32 + (lane & 15);
#pragma unroll
    for (int m = 0; m < 2; ++m)
#pragma unroll
        for (int n = 0; n < 2; ++n)
#pragma unroll
            for (int r = 0; r < 4; ++r)
                Mt[(size_t)(row0 + m * 16 + r) * 1024 + col0 + n * 16] =
                    __float2bfloat16(acc[m][n][r] * 0.03125f);
}

// ================= 256x256 2-phase overlap mainloop (R6 schedule — best measured) =================
static constexpr int NT256 = 16;  // K=1024 / BK=64

__device__ __forceinline__ void gemm256_mainloop(const bf16* __restrict__ Ag,
                                                 const bf16* __restrict__ Bg,
                                                 char* lds, f32x4 acc[8][4]) {
    const int tid = threadIdx.x;
    const int lane = tid & 63;
    const int wid = tid >> 6;
    const int wm = wid >> 2;   // 0..1
    const int wn = wid & 3;    // 0..3

#pragma unroll
    for (int m = 0; m < 8; ++m)
#pragma unroll
        for (int n = 0; n < 4; ++n) { acc[m][n][0]=0.f; acc[m][n][1]=0.f; acc[m][n][2]=0.f; acc[m][n][3]=0.f; }

    char* A0 = lds;            char* B0 = lds + 32768;
    char* A1 = lds + 65536;    char* B1 = lds + 98304;

    // ---- hoisted stage source offsets (elements) ----
    int soA[2], soB[2];
    {
#pragma unroll
        for (int i = 0; i < 2; ++i) {
            int beta = (i * 512 + tid) * 16;
            int rho  = beta >> 7;
            int cs   = (beta & 127) ^ ((rho & 7) << 4);
            soA[i] = ((rho >> 6) * 128 + (rho & 63)) * 1024 + (cs >> 1);
            soB[i] = ((rho >> 5) * 64  + (rho & 31)) * 1024 + (cs >> 1);
        }
    }
    const int dstw = wid * 1024;  // wave-uniform lds dst base within region half

    // ---- hoisted ds_read byte offsets (lower halves; upper = +16384, kk=1 = ^64) ----
    int roA[4], roB[2];
    {
        const int swz = (lane & 7) << 4;
        const int colb = (lane >> 4) * 16;
#pragma unroll
        for (int mi = 0; mi < 4; ++mi) {
            int row = wm * 64 + mi * 16 + (lane & 15);
            roA[mi] = (row * 128 + colb) ^ swz;
        }
#pragma unroll
        for (int ni = 0; ni < 2; ++ni) {
            int row = wn * 32 + ni * 16 + (lane & 15);
            roB[ni] = (row * 128 + colb) ^ swz;
        }
    }

#define STAGE_A256(buf, q, kt)                                                        \
    {                                                                                 \
        async_copy16((bf16*)((buf) + (q) * 16384 + dstw),                             \
                     Ag + soA[0] + (q) * 65536 + (kt) * 64);                          \
        async_copy16((bf16*)((buf) + (q) * 16384 + 8192 + dstw),                      \
                     Ag + soA[1] + (q) * 65536 + (kt) * 64);                          \
    }
#define STAGE_B256(buf, q, kt)                                                        \
    {                                                                                 \
        async_copy16((bf16*)((buf) + (q) * 16384 + dstw),                             \
                     Bg + soB[0] + (q) * 32768 + (kt) * 64);                          \
        async_copy16((bf16*)((buf) + (q) * 16384 + 8192 + dstw),                      \
                     Bg + soB[1] + (q) * 32768 + (kt) * 64);                          \
    }

    // Prologue: tile0 fully + tile1 {A0,B0}; wait the 8 oldest (tile0).
    STAGE_A256(A0, 0, 0); STAGE_A256(A0, 1, 0);
    STAGE_B256(B0, 0, 0); STAGE_B256(B0, 1, 0);
    STAGE_A256(A1, 0, 1); STAGE_B256(B1, 0, 1);
    asm volatile("s_waitcnt vmcnt(4)" ::: "memory");
    __builtin_amdgcn_s_barrier();

    short8 a[4][2], b0[2][2], b1[2][2];

#pragma unroll 1
    for (int t = 0; t < NT256; ++t) {
        char* As  = (t & 1) ? A1 : A0;
        char* Bs  = (t & 1) ? B1 : B0;
        char* Aso = (t & 1) ? A0 : A1;
        char* Bso = (t & 1) ? B0 : B1;

        // ======== top half: quadrants (0,0) then (0,1) ========
#pragma unroll
        for (int ni = 0; ni < 2; ++ni) {
            b0[ni][0] = *reinterpret_cast<const short8*>(Bs + roB[ni]);
            b0[ni][1] = *reinterpret_cast<const short8*>(Bs + (roB[ni] ^ 64));
        }
#pragma unroll
        for (int mi = 0; mi < 4; ++mi) {
            a[mi][0] = *reinterpret_cast<const short8*>(As + roA[mi]);
            a[mi][1] = *reinterpret_cast<const short8*>(As + (roA[mi] ^ 64));
        }
#pragma unroll
        for (int ni = 0; ni < 2; ++ni) {
            b1[ni][0] = *reinterpret_cast<const short8*>(Bs + (roB[ni] + 16384));
            b1[ni][1] = *reinterpret_cast<const short8*>(Bs + ((roB[ni] ^ 64) + 16384));
        }
        if (t + 1 < NT256) { STAGE_A256(Aso, 1, t + 1); STAGE_B256(Bso, 1, t + 1); }
        __builtin_amdgcn_s_setprio(1);
#pragma unroll
        for (int mi = 0; mi < 4; ++mi)
#pragma unroll
            for (int ni = 0; ni < 2; ++ni)
#pragma unroll
                for (int kk = 0; kk < 2; ++kk)
                    acc[mi][ni] = __builtin_amdgcn_mfma_f32_16x16x32_bf16(
                        a[mi][kk], b0[ni][kk], acc[mi][ni], 0, 0, 0);
#pragma unroll
        for (int mi = 0; mi < 4; ++mi)
#pragma unroll
            for (int ni = 0; ni < 2; ++ni)
#pragma unroll
                for (int kk = 0; kk < 2; ++kk)
                    acc[mi][2 + ni] = __builtin_amdgcn_mfma_f32_16x16x32_bf16(
                        a[mi][kk], b1[ni][kk], acc[mi][2 + ni], 0, 0, 0);
        __builtin_amdgcn_s_setprio(0);
        __builtin_amdgcn_sched_barrier(0);   // pin MFMAs + their lgkm waits above the barrier
        __builtin_amdgcn_s_barrier();        // all waves' q0-region reads complete

        // ======== bottom half: quadrants (1,1) then (1,0) ========
        if (t + 2 < NT256) { STAGE_A256(As, 0, t + 2); STAGE_B256(Bs, 0, t + 2); }
#pragma unroll
        for (int mi = 0; mi < 4; ++mi) {
            a[mi][0] = *reinterpret_cast<const short8*>(As + (roA[mi] + 16384));
            a[mi][1] = *reinterpret_cast<const short8*>(As + ((roA[mi] ^ 64) + 16384));
        }
        __builtin_amdgcn_s_setprio(1);
#pragma unroll
        for (int mi = 0; mi < 4; ++mi)
#pragma unroll
            for (int ni = 0; ni < 2; ++ni)
#pragma unroll
                for (int kk = 0; kk < 2; ++kk)
                    acc[4 + mi][2 + ni] = __builtin_amdgcn_mfma_f32_16x16x32_bf16(
                        a[mi][kk], b1[ni][kk], acc[4 + mi][2 + ni], 0, 0, 0);
#pragma unroll
        for (int mi = 0; mi < 4; ++mi)
#pragma unroll
            for (int ni = 0; ni < 2; ++ni)
#pragma unroll
                for (int kk = 0; kk < 2; ++kk)
                    acc[4 + mi][ni] = __builtin_amdgcn_mfma_f32_16x16x32_bf16(
                        a[mi][kk], b0[ni][kk], acc[4 + mi][ni], 0, 0, 0);
        __builtin_amdgcn_s_setprio(0);
        __builtin_amdgcn_sched_barrier(0);   // pin a1 reads/waits above the boundary
        if (t + 2 < NT256) asm volatile("s_waitcnt vmcnt(4)" ::: "memory");
        else               asm volatile("s_waitcnt vmcnt(0)" ::: "memory");
        __builtin_amdgcn_s_barrier();        // tile boundary: tile t+1 fully landed
    }
#undef STAGE_A256
#undef STAGE_B256
}

// ---------------- G = xb @ Mt^T  (32768x1024), 256², plain 2-D grid ----------------
__global__ __launch_bounds__(512, 2) void gemm_g256(const bf16* __restrict__ xb,
                                                    const bf16* __restrict__ Mt,
                                                    bf16* __restrict__ G) {
    extern __shared__ char lds[];
    f32x4 acc[8][4];
    const int bx = blockIdx.x, by = blockIdx.y;
    gemm256_mainloop(xb + (size_t)by * 256 * 1024, Mt + (size_t)bx * 256 * 1024, lds, acc);
    const int lane = threadIdx.x & 63, wid = threadIdx.x >> 6;
    const int wm = wid >> 2, wn = wid & 3;
    const int row0 = by * 256 + wm * 128 + ((lane >> 4) << 2);
    const int col0 = bx * 256 + wn * 64 + (lane & 15);
#pragma unroll
    for (int mi = 0; mi < 8; ++mi)
#pragma unroll
        for (int ni = 0; ni < 4; ++ni)
#pragma unroll
            for (int r = 0; r < 4; ++r)
                G[(size_t)(row0 + mi * 16 + r) * 1024 + col0 + ni * 16] =
                    __float2bfloat16(acc[mi][ni][r]);
}

// ---------------- energy: E = G @ xb^T, PT[k][q] = fp8(exp(E)) packed, lsum += rowsum ----------------
__global__ __launch_bounds__(512, 2) void energy_fused256(const bf16* __restrict__ G,
                                                          const bf16* __restrict__ xb,
                                                          unsigned char* __restrict__ PT,
                                                          float* __restrict__ lsum) {
    extern __shared__ char lds[];
    f32x4 acc[8][4];
    const int bx = blockIdx.x, by = blockIdx.y, bz = blockIdx.z;
    gemm256_mainloop(G + (size_t)(bz * 2048 + by * 256) * 1024,
                     xb + (size_t)(bz * 2048 + bx * 256) * 1024, lds, acc);
    const int lane = threadIdx.x & 63, wid = threadIdx.x >> 6;
    const int wm = wid >> 2, wn = wid & 3;
    const int q0g = bz * 2048 + by * 256 + wm * 128 + ((lane >> 4) << 2);  // global q row (lsum idx)
    const int ql0 = by * 256 + wm * 128 + ((lane >> 4) << 2);              // q col within batch (PT col)
    const int kl0 = bx * 256 + wn * 64 + (lane & 15);                      // k row within batch (PT row)
#pragma unroll
    for (int mi = 0; mi < 8; ++mi) {
        float s[4] = {0.f, 0.f, 0.f, 0.f};
#pragma unroll
        for (int ni = 0; ni < 4; ++ni) {
            unsigned pack = 0;
#pragma unroll
            for (int r = 0; r < 4; ++r) {
                float e = fast_exp(acc[mi][ni][r]);
                unsigned char c = f32_to_e4m3(e);
                pack |= (unsigned)c << (8 * r);
                s[r] += e4m3_to_f32(c);
            }
            // PT[bz][kl0 + ni*16][ql0 + mi*16 .. +3]  (r packs 4 consecutive q)
            *reinterpret_cast<unsigned*>(
                PT + ((size_t)(bz * 2048 + kl0 + ni * 16) * 2048) + ql0 + mi * 16) = pack;
        }
#pragma unroll
        for (int off = 1; off < 16; off <<= 1)
#pragma unroll
            for (int r = 0; r < 4; ++r) s[r] += __shfl_xor(s[r], off, 64);
        if ((lane & 15) == 0) {
#pragma unroll
            for (int r = 0; r < 4; ++r) atomicAdd(&lsum[q0g + mi * 16 + r], s[r]);
        }
    }
}

// ---------------- aw[b,k] = (1/S) sum_q dec(PT[b][k][q]) / lsum[b,q]  (wave per k-row) ----------------
__global__ __launch_bounds__(256) void colsum_kernel(const unsigned char* __restrict__ PT,
                                                     const float* __restrict__ lsum,
                                                     float* __restrict__ aw) {
    const int b = blockIdx.y;
    const int wid = threadIdx.x >> 6, lane = threadIdx.x & 63;
    const int k = blockIdx.x * 4 + wid;           // k-row
    const unsigned char* row = PT + (size_t)(b * 2048 + k) * 2048;
    const float* ls = lsum + b * 2048;
    float s = 0.f;
#pragma unroll
    for (int it = 0; it < 8; ++it) {
        int q = (it * 64 + lane) * 4;             // 4 consecutive q per lane
        unsigned v = *reinterpret_cast<const unsigned*>(row + q);
        float4 l4 = *reinterpret_cast<const float4*>(ls + q);
        s += e4m3_to_f32((unsigned char)(v & 0xff)) / l4.x;
        s += e4m3_to_f32((unsigned char)((v >> 8) & 0xff)) / l4.y;
        s += e4m3_to_f32((unsigned char)((v >> 16) & 0xff)) / l4.z;
        s += e4m3_to_f32((unsigned char)((v >> 24) & 0xff)) / l4.w;
    }
#pragma unroll
    for (int off = 1; off < 64; off <<= 1) s += __shfl_xor(s, off, 64);
    if (lane == 0) aw[b * 2048 + k] = s * (1.0f / 2048.0f);
}

// ---------------- t[b,h] = sum_k aw[b,k] * xb[b,k,h]  (bf16 x) ----------------
__global__ __launch_bounds__(256) void av_x_kernel(const float* __restrict__ aw,
                                                   const bf16* __restrict__ xb,
                                                   float* __restrict__ t) {
    const int b = blockIdx.y;
    const int kc = blockIdx.x;
    const int tid = threadIdx.x;
    float4 acc = {0.f, 0.f, 0.f, 0.f};
    const int k0 = kc * 128;
#pragma unroll 4
    for (int k = k0; k < k0 + 128; ++k) {
        float w = aw[b * 2048 + k];
        uint2 v = *reinterpret_cast<const uint2*>(xb + (size_t)(b * 2048 + k) * 1024 + tid * 4);
        acc.x += w * bf2f((unsigned short)(v.x & 0xffff));
        acc.y += w * bf2f((unsigned short)(v.x >> 16));
        acc.z += w * bf2f((unsigned short)(v.y & 0xffff));
        acc.w += w * bf2f((unsigned short)(v.y >> 16));
    }
    float* tp = t + b * 1024 + tid * 4;
    atomicAdd(tp + 0, acc.x); atomicAdd(tp + 1, acc.y);
    atomicAdd(tp + 2, acc.z); atomicAdd(tp + 3, acc.w);
}

// ---------------- context[b,o] = sum_h t[b,h] * W_v[o,h] ----------------
__global__ __launch_bounds__(256) void ctx_gemv_kernel(const float* __restrict__ t,
                                                       const float* __restrict__ wv,
                                                       float* __restrict__ ctx) {
    const int b = blockIdx.y;
    const int wid = threadIdx.x >> 6, lane = threadIdx.x & 63;
    const int o = blockIdx.x * 4 + wid;
    const float4* t4 = reinterpret_cast<const float4*>(t + b * 1024);
    const float4* w4 = reinterpret_cast<const float4*>(wv + (size_t)o * 1024);
    float s = 0.f;
#pragma unroll
    for (int j = lane; j < 256; j += 64) {
        float4 a = t4[j], w = w4[j];
        s += a.x * w.x + a.y * w.y + a.z * w.z + a.w * w.w;
    }
#pragma unroll
    for (int off = 1; off < 64; off <<= 1) s += __shfl_xor(s, off, 64);
    if (lane == 0) ctx[b * 1024 + o] = s;
}

__global__ void ws_too_small_kernel(float* out) {
    if (threadIdx.x == 0 && blockIdx.x == 0) out[0] = 12345.0f;
}

extern "C" void kernel_launch(void* const* d_in, const int* in_sizes, int n_in,
                              void* d_out, int out_size, void* d_ws, size_t ws_size,
                              hipStream_t stream) {
    const float* x  = (const float*)d_in[0];
    const float* wq = (const float*)d_in[1];
    const float* wk = (const float*)d_in[2];
    const float* wv = (const float*)d_in[3];
    float* out = (float*)d_out;
    float* ctx = out;           // 16*1024
    float* aw  = out + 16384;   // 16*2048

    if (ws_size < WS_NEED) {
        hipMemsetAsync(d_out, 0, (size_t)out_size * sizeof(float), stream);
        ws_too_small_kernel<<<1, 64, 0, stream>>>(out);
        return;
    }

    char* ws = (char*)d_ws;
    bf16* xb   = (bf16*)(ws + WS_XB);
    bf16* G    = (bf16*)(ws + WS_G);
    unsigned char* PT = (unsigned char*)(ws + WS_P);
    bf16* wqT  = (bf16*)(ws + WS_WQT);
    bf16* wkT  = (bf16*)(ws + WS_WKT);
    bf16* Mt   = (bf16*)(ws + WS_MT);
    float* lsum = (float*)(ws + WS_LSUM);
    float* t    = (float*)(ws + WS_T);

    hipMemsetAsync(d_out, 0, (size_t)out_size * sizeof(float), stream);
    hipMemsetAsync(lsum, 0, 131072 + 65536, stream);  // lsum + t contiguous

    cast_x_kernel<<<2048, 256, 0, stream>>>(x, xb, (BB * SS * HH) / 4);
    transpose_w_kernel<<<dim3(16, 16, 2), 256, 0, stream>>>(wq, wk, wqT, wkT);

    gemm_mt64<<<dim3(16, 16), 256, 0, stream>>>(wkT, wqT, Mt);
    gemm_g256<<<dim3(4, 128), 512, 131072, stream>>>(xb, Mt, G);

    energy_fused256<<<dim3(8, 8, 16), 512, 131072, stream>>>(G, xb, PT, lsum);
    colsum_kernel<<<dim3(512, 16), 256, 0, stream>>>(PT, lsum, aw);

    av_x_kernel<<<dim3(16, 16), 256, 0, stream>>>(aw, xb, t);
    ctx_gemv_kernel<<<dim3(256, 16), 256, 0, stream>>>(t, wv, ctx);
}

// Round 10
// 316.964 us; speedup vs baseline: 1.0413x; 1.0343x over previous
//
#include <hip/hip_runtime.h>
#include <hip/hip_bf16.h>
#include <stdint.h>

// Problem constants
#define BB 16
#define SS 2048
#define HH 1024

using bf16 = __hip_bfloat16;
typedef __attribute__((ext_vector_type(8))) short short8;
typedef __attribute__((ext_vector_type(4))) float f32x4;

typedef unsigned int __attribute__((address_space(1))) as1_uint;
typedef unsigned int __attribute__((address_space(3))) as3_uint;

// ---------------- workspace layout (bytes) ----------------
static constexpr size_t WS_XB   = 0;          // bf16[16*2048*1024]
static constexpr size_t WS_G    = 67108864;   // bf16[32768*1024]
static constexpr size_t WS_P    = 134217728;  // fp8 P[b][q][k]
static constexpr size_t WS_WQT  = 134217728;  // aliased, dead before P written
static constexpr size_t WS_WKT  = 136314880;
static constexpr size_t WS_MT   = 138412032;
static constexpr size_t WS_LSUM = 201326592;  // f32[32768]
static constexpr size_t WS_T    = 201457664;  // f32[16*1024]
static constexpr size_t WS_NEED = 201523200;

__device__ __forceinline__ void async_copy16(bf16* lds_dst, const bf16* gsrc) {
    __builtin_amdgcn_global_load_lds((const as1_uint*)gsrc, (as3_uint*)lds_dst, 16, 0, 0);
}

__device__ __forceinline__ float bf2f(unsigned short u) {
    union { unsigned i; float f; } v; v.i = (unsigned)u << 16; return v.f;
}

// ---------------- fp8 e4m3 encode/decode ----------------
__device__ __forceinline__ unsigned char f32_to_e4m3(float x) {
#if __has_builtin(__builtin_amdgcn_cvt_pk_fp8_f32)
    return (unsigned char)(__builtin_amdgcn_cvt_pk_fp8_f32(x, x, 0, false) & 0xff);
#else
    if (x >= 0.015625f) {
        union { float f; unsigned u; } v; v.f = x;
        int e = (v.u >> 23) & 0xff;
        unsigned m = v.u & 0x7fffff;
        unsigned mant = m >> 20;
        unsigned rem = m & 0xfffff;
        mant += (rem > 0x80000u) || (rem == 0x80000u && (mant & 1));
        int oe = e - 120;
        if (mant == 8) { mant = 0; oe += 1; }
        return (unsigned char)((oe << 3) | mant);
    }
    int code = (int)rintf(x * 512.0f);
    return (unsigned char)code;
#endif
}

__device__ __forceinline__ float e4m3_to_f32(unsigned char b) {
#if __has_builtin(__builtin_amdgcn_cvt_pk_f32_fp8)
    auto v = __builtin_amdgcn_cvt_pk_f32_fp8((int)b, false);
    return v[0];
#else
    int e = (b >> 3) & 15, m = b & 7;
    if (e) { union { unsigned u; float f; } v; v.u = ((unsigned)(e + 120) << 23) | ((unsigned)m << 20); return v.f; }
    return (float)m * 0.001953125f;
#endif
}

// ---------------- cast x -> bf16 ----------------
__global__ __launch_bounds__(256) void cast_x_kernel(const float* __restrict__ x,
                                                     bf16* __restrict__ xb, int n4) {
    int stride = gridDim.x * blockDim.x;
    for (int i = blockIdx.x * blockDim.x + threadIdx.x; i < n4; i += stride) {
        float4 v = reinterpret_cast<const float4*>(x)[i];
        union { bf16 h[4]; uint2 u; } p;
        p.h[0] = __float2bfloat16(v.x); p.h[1] = __float2bfloat16(v.y);
        p.h[2] = __float2bfloat16(v.z); p.h[3] = __float2bfloat16(v.w);
        reinterpret_cast<uint2*>(xb)[i] = p.u;
    }
}

// ---------------- transpose-cast W -> WT bf16 (i,o) ----------------
__global__ __launch_bounds__(256) void transpose_w_kernel(const float* __restrict__ wq,
                                                          const float* __restrict__ wk,
                                                          bf16* __restrict__ wqT,
                                                          bf16* __restrict__ wkT) {
    __shared__ float tile[64][65];
    const float* src = blockIdx.z ? wk : wq;
    bf16* dst = blockIdx.z ? wkT : wqT;
    const int o0 = blockIdx.y * 64, i0 = blockIdx.x * 64;
    const int tr = threadIdx.x >> 4;
    const int tc = (threadIdx.x & 15) * 4;
#pragma unroll
    for (int k = 0; k < 4; ++k) {
        float4 v = *reinterpret_cast<const float4*>(src + (size_t)(o0 + tr + k * 16) * 1024 + i0 + tc);
        tile[tr + k * 16][tc + 0] = v.x; tile[tr + k * 16][tc + 1] = v.y;
        tile[tr + k * 16][tc + 2] = v.z; tile[tr + k * 16][tc + 3] = v.w;
    }
    __syncthreads();
#pragma unroll
    for (int k = 0; k < 4; ++k) {
        int ri = tr + k * 16;
        union { bf16 h[4]; uint2 u; } p;
#pragma unroll
        for (int j = 0; j < 4; ++j) p.h[j] = __float2bfloat16(tile[tc + j][ri]);
        *reinterpret_cast<uint2*>(dst + (size_t)(i0 + ri) * 1024 + o0 + tc) = p.u;
    }
}

// ---------------- gemm_mt64: Mt[j][i] = (1/32) sum_o Wk[o,j]*Wq[o,i], 64x64 tiles ----------------
__global__ __launch_bounds__(256) void gemm_mt64(const bf16* __restrict__ wkT,
                                                 const bf16* __restrict__ wqT,
                                                 bf16* __restrict__ Mt) {
    __shared__ bf16 As[64 * 64], Bs[64 * 64];
    f32x4 acc[2][2];
#pragma unroll
    for (int m = 0; m < 2; ++m)
#pragma unroll
        for (int n = 0; n < 2; ++n) { acc[m][n][0]=0.f; acc[m][n][1]=0.f; acc[m][n][2]=0.f; acc[m][n][3]=0.f; }
    const int tid = threadIdx.x, wid = tid >> 6, lane = tid & 63;
    const int wm = wid >> 1, wn = wid & 1;
    const int srow = lane >> 3, scol = (lane & 7) * 8;
    const bf16* Ab = wkT + (size_t)blockIdx.y * 64 * 1024;
    const bf16* Bb = wqT + (size_t)blockIdx.x * 64 * 1024;
    for (int kt = 0; kt < 1024; kt += 64) {
#pragma unroll
        for (int i = 0; i < 2; ++i) {
            int row0 = i * 32 + wid * 8;  // wave-uniform
            async_copy16(As + row0 * 64, Ab + (size_t)(row0 + srow) * 1024 + kt + scol);
            async_copy16(Bs + row0 * 64, Bb + (size_t)(row0 + srow) * 1024 + kt + scol);
        }
        __syncthreads();
#pragma unroll
        for (int kk = 0; kk < 2; ++kk) {
            short8 a[2], b[2];
#pragma unroll
            for (int m = 0; m < 2; ++m)
                a[m] = *reinterpret_cast<const short8*>(
                    As + (wm * 32 + m * 16 + (lane & 15)) * 64 + kk * 32 + (lane >> 4) * 8);
#pragma unroll
            for (int n = 0; n < 2; ++n)
                b[n] = *reinterpret_cast<const short8*>(
                    Bs + (wn * 32 + n * 16 + (lane & 15)) * 64 + kk * 32 + (lane >> 4) * 8);
#pragma unroll
            for (int m = 0; m < 2; ++m)
#pragma unroll
                for (int n = 0; n < 2; ++n)
                    acc[m][n] = __builtin_amdgcn_mfma_f32_16x16x32_bf16(a[m], b[n], acc[m][n], 0, 0, 0);
        }
        __syncthreads();
    }
    const int row0 = blockIdx.y * 64 + wm * 32 + ((lane >> 4) << 2);
    const int col0 = blockIdx.x * 64 + wn * 32 + (lane & 15);
#pragma unroll
    for (int m = 0; m < 2; ++m)
#pragma unroll
        for (int n = 0; n < 2; ++n)
#pragma unroll
            for (int r = 0; r < 4; ++r)
                Mt[(size_t)(row0 + m * 16 + r) * 1024 + col0 + n * 16] =
                    __float2bfloat16(acc[m][n][r] * 0.03125f);
}

// ================= 256x256 2-phase overlap mainloop (R6 schedule — best measured) =================
static constexpr int NT256 = 16;  // K=1024 / BK=64

__device__ __forceinline__ void gemm256_mainloop(const bf16* __restrict__ Ag,
                                                 const bf16* __restrict__ Bg,
                                                 char* lds, f32x4 acc[8][4]) {
    const int tid = threadIdx.x;
    const int lane = tid & 63;
    const int wid = tid >> 6;
    const int wm = wid >> 2;   // 0..1
    const int wn = wid & 3;    // 0..3

#pragma unroll
    for (int m = 0; m < 8; ++m)
#pragma unroll
        for (int n = 0; n < 4; ++n) { acc[m][n][0]=0.f; acc[m][n][1]=0.f; acc[m][n][2]=0.f; acc[m][n][3]=0.f; }

    char* A0 = lds;            char* B0 = lds + 32768;
    char* A1 = lds + 65536;    char* B1 = lds + 98304;

    // ---- hoisted stage source offsets (elements) ----
    int soA[2], soB[2];
    {
#pragma unroll
        for (int i = 0; i < 2; ++i) {
            int beta = (i * 512 + tid) * 16;
            int rho  = beta >> 7;
            int cs   = (beta & 127) ^ ((rho & 7) << 4);
            soA[i] = ((rho >> 6) * 128 + (rho & 63)) * 1024 + (cs >> 1);
            soB[i] = ((rho >> 5) * 64  + (rho & 31)) * 1024 + (cs >> 1);
        }
    }
    const int dstw = wid * 1024;  // wave-uniform lds dst base within region half

    // ---- hoisted ds_read byte offsets (lower halves; upper = +16384, kk=1 = ^64) ----
    int roA[4], roB[2];
    {
        const int swz = (lane & 7) << 4;
        const int colb = (lane >> 4) * 16;
#pragma unroll
        for (int mi = 0; mi < 4; ++mi) {
            int row = wm * 64 + mi * 16 + (lane & 15);
            roA[mi] = (row * 128 + colb) ^ swz;
        }
#pragma unroll
        for (int ni = 0; ni < 2; ++ni) {
            int row = wn * 32 + ni * 16 + (lane & 15);
            roB[ni] = (row * 128 + colb) ^ swz;
        }
    }

#define STAGE_A256(buf, q, kt)                                                        \
    {                                                                                 \
        async_copy16((bf16*)((buf) + (q) * 16384 + dstw),                             \
                     Ag + soA[0] + (q) * 65536 + (kt) * 64);                          \
        async_copy16((bf16*)((buf) + (q) * 16384 + 8192 + dstw),                      \
                     Ag + soA[1] + (q) * 65536 + (kt) * 64);                          \
    }
#define STAGE_B256(buf, q, kt)                                                        \
    {                                                                                 \
        async_copy16((bf16*)((buf) + (q) * 16384 + dstw),                             \
                     Bg + soB[0] + (q) * 32768 + (kt) * 64);                          \
        async_copy16((bf16*)((buf) + (q) * 16384 + 8192 + dstw),                      \
                     Bg + soB[1] + (q) * 32768 + (kt) * 64);                          \
    }

    // Prologue: tile0 fully + tile1 {A0,B0}; wait the 8 oldest (tile0).
    STAGE_A256(A0, 0, 0); STAGE_A256(A0, 1, 0);
    STAGE_B256(B0, 0, 0); STAGE_B256(B0, 1, 0);
    STAGE_A256(A1, 0, 1); STAGE_B256(B1, 0, 1);
    asm volatile("s_waitcnt vmcnt(4)" ::: "memory");
    __builtin_amdgcn_s_barrier();

    short8 a[4][2], b0[2][2], b1[2][2];

#pragma unroll 1
    for (int t = 0; t < NT256; ++t) {
        char* As  = (t & 1) ? A1 : A0;
        char* Bs  = (t & 1) ? B1 : B0;
        char* Aso = (t & 1) ? A0 : A1;
        char* Bso = (t & 1) ? B0 : B1;

        // ======== top half: quadrants (0,0) then (0,1) ========
#pragma unroll
        for (int ni = 0; ni < 2; ++ni) {
            b0[ni][0] = *reinterpret_cast<const short8*>(Bs + roB[ni]);
            b0[ni][1] = *reinterpret_cast<const short8*>(Bs + (roB[ni] ^ 64));
        }
#pragma unroll
        for (int mi = 0; mi < 4; ++mi) {
            a[mi][0] = *reinterpret_cast<const short8*>(As + roA[mi]);
            a[mi][1] = *reinterpret_cast<const short8*>(As + (roA[mi] ^ 64));
        }
#pragma unroll
        for (int ni = 0; ni < 2; ++ni) {
            b1[ni][0] = *reinterpret_cast<const short8*>(Bs + (roB[ni] + 16384));
            b1[ni][1] = *reinterpret_cast<const short8*>(Bs + ((roB[ni] ^ 64) + 16384));
        }
        if (t + 1 < NT256) { STAGE_A256(Aso, 1, t + 1); STAGE_B256(Bso, 1, t + 1); }
        __builtin_amdgcn_s_setprio(1);
#pragma unroll
        for (int mi = 0; mi < 4; ++mi)
#pragma unroll
            for (int ni = 0; ni < 2; ++ni)
#pragma unroll
                for (int kk = 0; kk < 2; ++kk)
                    acc[mi][ni] = __builtin_amdgcn_mfma_f32_16x16x32_bf16(
                        a[mi][kk], b0[ni][kk], acc[mi][ni], 0, 0, 0);
#pragma unroll
        for (int mi = 0; mi < 4; ++mi)
#pragma unroll
            for (int ni = 0; ni < 2; ++ni)
#pragma unroll
                for (int kk = 0; kk < 2; ++kk)
                    acc[mi][2 + ni] = __builtin_amdgcn_mfma_f32_16x16x32_bf16(
                        a[mi][kk], b1[ni][kk], acc[mi][2 + ni], 0, 0, 0);
        __builtin_amdgcn_s_setprio(0);
        __builtin_amdgcn_sched_barrier(0);   // pin MFMAs + their lgkm waits above the barrier
        __builtin_amdgcn_s_barrier();        // all waves' q0-region reads complete

        // ======== bottom half: quadrants (1,1) then (1,0) ========
        if (t + 2 < NT256) { STAGE_A256(As, 0, t + 2); STAGE_B256(Bs, 0, t + 2); }
#pragma unroll
        for (int mi = 0; mi < 4; ++mi) {
            a[mi][0] = *reinterpret_cast<const short8*>(As + (roA[mi] + 16384));
            a[mi][1] = *reinterpret_cast<const short8*>(As + ((roA[mi] ^ 64) + 16384));
        }
        __builtin_amdgcn_s_setprio(1);
#pragma unroll
        for (int mi = 0; mi < 4; ++mi)
#pragma unroll
            for (int ni = 0; ni < 2; ++ni)
#pragma unroll
                for (int kk = 0; kk < 2; ++kk)
                    acc[4 + mi][2 + ni] = __builtin_amdgcn_mfma_f32_16x16x32_bf16(
                        a[mi][kk], b1[ni][kk], acc[4 + mi][2 + ni], 0, 0, 0);
#pragma unroll
        for (int mi = 0; mi < 4; ++mi)
#pragma unroll
            for (int ni = 0; ni < 2; ++ni)
#pragma unroll
                for (int kk = 0; kk < 2; ++kk)
                    acc[4 + mi][ni] = __builtin_amdgcn_mfma_f32_16x16x32_bf16(
                        a[mi][kk], b0[ni][kk], acc[4 + mi][ni], 0, 0, 0);
        __builtin_amdgcn_s_setprio(0);
        __builtin_amdgcn_sched_barrier(0);   // pin a1 reads/waits above the boundary
        if (t + 2 < NT256) asm volatile("s_waitcnt vmcnt(4)" ::: "memory");
        else               asm volatile("s_waitcnt vmcnt(0)" ::: "memory");
        __builtin_amdgcn_s_barrier();        // tile boundary: tile t+1 fully landed
    }
#undef STAGE_A256
#undef STAGE_B256
}

// ---------------- G = xb @ Mt^T  (32768x1024), 256² ----------------
__global__ __launch_bounds__(512, 2) void gemm_g256(const bf16* __restrict__ xb,
                                                    const bf16* __restrict__ Mt,
                                                    bf16* __restrict__ G) {
    extern __shared__ char lds[];
    f32x4 acc[8][4];
    const int bx = blockIdx.x, by = blockIdx.y;
    gemm256_mainloop(xb + (size_t)by * 256 * 1024, Mt + (size_t)bx * 256 * 1024, lds, acc);
    const int lane = threadIdx.x & 63, wid = threadIdx.x >> 6;
    const int wm = wid >> 2, wn = wid & 3;
    const int row0 = by * 256 + wm * 128 + ((lane >> 4) << 2);
    const int col0 = bx * 256 + wn * 64 + (lane & 15);
#pragma unroll
    for (int mi = 0; mi < 8; ++mi)
#pragma unroll
        for (int ni = 0; ni < 4; ++ni)
#pragma unroll
            for (int r = 0; r < 4; ++r)
                G[(size_t)(row0 + mi * 16 + r) * 1024 + col0 + ni * 16] =
                    __float2bfloat16(acc[mi][ni][r]);
}

// ---------------- energy: E = G @ xb^T, P = fp8(exp(E)), lsum += rowsum(dec(P)) ----------------
__global__ __launch_bounds__(512, 2) void energy_fused256(const bf16* __restrict__ G,
                                                          const bf16* __restrict__ xb,
                                                          unsigned char* __restrict__ P,
                                                          float* __restrict__ lsum) {
    extern __shared__ char lds[];
    f32x4 acc[8][4];
    const int bx = blockIdx.x, by = blockIdx.y, bz = blockIdx.z;
    gemm256_mainloop(G + (size_t)(bz * 2048 + by * 256) * 1024,
                     xb + (size_t)(bz * 2048 + bx * 256) * 1024, lds, acc);
    const int lane = threadIdx.x & 63, wid = threadIdx.x >> 6;
    const int wm = wid >> 2, wn = wid & 3;
    const int q0 = bz * 2048 + by * 256 + wm * 128 + ((lane >> 4) << 2);
    const int k0 = bx * 256 + wn * 64 + (lane & 15);
#pragma unroll
    for (int mi = 0; mi < 8; ++mi) {
        float s[4] = {0.f, 0.f, 0.f, 0.f};
#pragma unroll
        for (int ni = 0; ni < 4; ++ni)
#pragma unroll
            for (int r = 0; r < 4; ++r) {
                float e = __expf(acc[mi][ni][r]);
                unsigned char c = f32_to_e4m3(e);
                P[(size_t)(q0 + mi * 16 + r) * 2048 + k0 + ni * 16] = c;
                s[r] += e4m3_to_f32(c);
            }
#pragma unroll
        for (int off = 1; off < 16; off <<= 1)
#pragma unroll
            for (int r = 0; r < 4; ++r) s[r] += __shfl_xor(s[r], off, 64);
        if ((lane & 15) == 0) {
#pragma unroll
            for (int r = 0; r < 4; ++r) atomicAdd(&lsum[q0 + mi * 16 + r], s[r]);
        }
    }
}

// ---------------- aw[b,k] = (1/S) sum_q dec(P[b,q,k]) / lsum[b,q] ----------------
__global__ __launch_bounds__(256) void colsum_kernel(const unsigned char* __restrict__ P,
                                                     const float* __restrict__ lsum,
                                                     float* __restrict__ aw) {
    const int b = blockIdx.y, qc = blockIdx.x, t = threadIdx.x;
    float acc[8] = {0.f, 0.f, 0.f, 0.f, 0.f, 0.f, 0.f, 0.f};
    const unsigned char* base = P + (size_t)(b * 2048 + qc * 128) * 2048 + t * 8;
    const float* ls = lsum + b * 2048 + qc * 128;
    for (int q = 0; q < 128; ++q) {
        float w = 1.0f / ls[q];
        uint2 v = *reinterpret_cast<const uint2*>(base + (size_t)q * 2048);
#if __has_builtin(__builtin_amdgcn_cvt_pk_f32_fp8)
        auto p0 = __builtin_amdgcn_cvt_pk_f32_fp8((int)v.x, false);
        auto p1 = __builtin_amdgcn_cvt_pk_f32_fp8((int)v.x, true);
        auto p2 = __builtin_amdgcn_cvt_pk_f32_fp8((int)v.y, false);
        auto p3 = __builtin_amdgcn_cvt_pk_f32_fp8((int)v.y, true);
        acc[0] += p0[0] * w; acc[1] += p0[1] * w;
        acc[2] += p1[0] * w; acc[3] += p1[1] * w;
        acc[4] += p2[0] * w; acc[5] += p2[1] * w;
        acc[6] += p3[0] * w; acc[7] += p3[1] * w;
#else
        unsigned char by8[8];
        *reinterpret_cast<uint2*>(by8) = v;
#pragma unroll
        for (int j = 0; j < 8; ++j) acc[j] += e4m3_to_f32(by8[j]) * w;
#endif
    }
#pragma unroll
    for (int j = 0; j < 8; ++j)
        atomicAdd(&aw[b * 2048 + t * 8 + j], acc[j] * (1.0f / 2048.0f));
}

// ---------------- t[b,h] = sum_k aw[b,k] * xb[b,k,h]  (bf16 x) ----------------
__global__ __launch_bounds__(256) void av_x_kernel(const float* __restrict__ aw,
                                                   const bf16* __restrict__ xb,
                                                   float* __restrict__ t) {
    const int b = blockIdx.y;
    const int kc = blockIdx.x;
    const int tid = threadIdx.x;
    float4 acc = {0.f, 0.f, 0.f, 0.f};
    const int k0 = kc * 128;
#pragma unroll 4
    for (int k = k0; k < k0 + 128; ++k) {
        float w = aw[b * 2048 + k];
        uint2 v = *reinterpret_cast<const uint2*>(xb + (size_t)(b * 2048 + k) * 1024 + tid * 4);
        acc.x += w * bf2f((unsigned short)(v.x & 0xffff));
        acc.y += w * bf2f((unsigned short)(v.x >> 16));
        acc.z += w * bf2f((unsigned short)(v.y & 0xffff));
        acc.w += w * bf2f((unsigned short)(v.y >> 16));
    }
    float* tp = t + b * 1024 + tid * 4;
    atomicAdd(tp + 0, acc.x); atomicAdd(tp + 1, acc.y);
    atomicAdd(tp + 2, acc.z); atomicAdd(tp + 3, acc.w);
}

// ---------------- context[b,o] = sum_h t[b,h] * W_v[o,h] ----------------
__global__ __launch_bounds__(256) void ctx_gemv_kernel(const float* __restrict__ t,
                                                       const float* __restrict__ wv,
                                                       float* __restrict__ ctx) {
    const int b = blockIdx.y;
    const int wid = threadIdx.x >> 6, lane = threadIdx.x & 63;
    const int o = blockIdx.x * 4 + wid;
    const float4* t4 = reinterpret_cast<const float4*>(t + b * 1024);
    const float4* w4 = reinterpret_cast<const float4*>(wv + (size_t)o * 1024);
    float s = 0.f;
#pragma unroll
    for (int j = lane; j < 256; j += 64) {
        float4 a = t4[j], w = w4[j];
        s += a.x * w.x + a.y * w.y + a.z * w.z + a.w * w.w;
    }
#pragma unroll
    for (int off = 1; off < 64; off <<= 1) s += __shfl_xor(s, off, 64);
    if (lane == 0) ctx[b * 1024 + o] = s;
}

__global__ void ws_too_small_kernel(float* out) {
    if (threadIdx.x == 0 && blockIdx.x == 0) out[0] = 12345.0f;
}

extern "C" void kernel_launch(void* const* d_in, const int* in_sizes, int n_in,
                              void* d_out, int out_size, void* d_ws, size_t ws_size,
                              hipStream_t stream) {
    const float* x  = (const float*)d_in[0];
    const float* wq = (const float*)d_in[1];
    const float* wk = (const float*)d_in[2];
    const float* wv = (const float*)d_in[3];
    float* out = (float*)d_out;
    float* ctx = out;           // 16*1024
    float* aw  = out + 16384;   // 16*2048

    if (ws_size < WS_NEED) {
        hipMemsetAsync(d_out, 0, (size_t)out_size * sizeof(float), stream);
        ws_too_small_kernel<<<1, 64, 0, stream>>>(out);
        return;
    }

    char* ws = (char*)d_ws;
    bf16* xb   = (bf16*)(ws + WS_XB);
    bf16* G    = (bf16*)(ws + WS_G);
    unsigned char* P = (unsigned char*)(ws + WS_P);
    bf16* wqT  = (bf16*)(ws + WS_WQT);
    bf16* wkT  = (bf16*)(ws + WS_WKT);
    bf16* Mt   = (bf16*)(ws + WS_MT);
    float* lsum = (float*)(ws + WS_LSUM);
    float* t    = (float*)(ws + WS_T);

    hipMemsetAsync(d_out, 0, (size_t)out_size * sizeof(float), stream);
    hipMemsetAsync(lsum, 0, 131072 + 65536, stream);  // lsum + t contiguous

    cast_x_kernel<<<2048, 256, 0, stream>>>(x, xb, (BB * SS * HH) / 4);
    transpose_w_kernel<<<dim3(16, 16, 2), 256, 0, stream>>>(wq, wk, wqT, wkT);

    gemm_mt64<<<dim3(16, 16), 256, 0, stream>>>(wkT, wqT, Mt);
    gemm_g256<<<dim3(4, 128), 512, 131072, stream>>>(xb, Mt, G);

    energy_fused256<<<dim3(8, 8, 16), 512, 131072, stream>>>(G, xb, P, lsum);
    colsum_kernel<<<dim3(16, 16), 256, 0, stream>>>(P, lsum, aw);

    av_x_kernel<<<dim3(16, 16), 256, 0, stream>>>(aw, xb, t);
    ctx_gemv_kernel<<<dim3(256, 16), 256, 0, stream>>>(t, wv, ctx);
}